// Round 15
// baseline (12297.189 us; speedup 1.0000x reference)
//
#include <hip/hip_runtime.h>

#define BB 64
#define CXC 16
#define CYC 64
#define LL 32
#define MM 28
#define NN 1024
#define SP 784
#define KTOT 50176
#define NSTEPS 50
#define NSPLIT 49

using short8  = __attribute__((ext_vector_type(8))) short;
using floatx4 = __attribute__((ext_vector_type(4))) float;

typedef __attribute__((address_space(1))) unsigned int gu32;
typedef __attribute__((address_space(3))) unsigned int su32;

__device__ __forceinline__ ushort f2b(float v) {
    union { float f; unsigned u; } a; a.f = v;
    unsigned r = a.u + 0x7fff + ((a.u >> 16) & 1);   // RNE
    return (ushort)(r >> 16);
}
__device__ __forceinline__ unsigned pk2(float a, float b) {
    return (unsigned)f2b(a) | ((unsigned)f2b(b) << 16);
}
__device__ __forceinline__ float b2f(ushort u) {
    union { unsigned u; float f; } a; a.u = ((unsigned)u) << 16; return a.f;
}

// fp32 -> OCP e4m3fn, RNE, saturating at 448
__device__ __forceinline__ unsigned char f2e4(float v) {
    const unsigned u = __float_as_uint(v);
    const unsigned s = (u >> 24) & 0x80;
    float a = fabsf(v);
    if (a >= 448.f) return (unsigned char)(s | 0x7E);
    if (a < 0.015625f) {
        int q = (int)rintf(a * 512.f);
        return (unsigned char)(s | (unsigned)q);
    }
    unsigned au = u & 0x7fffffffu;
    unsigned r = au + 0xFFFFFu + ((au >> 20) & 1u);
    int exp = (int)(r >> 23) - 127;
    if (exp > 8) return (unsigned char)(s | 0x7E);
    unsigned mant = (r >> 20) & 7u;
    return (unsigned char)(s | (((unsigned)(exp + 7)) << 3) | mant);
}

__device__ __forceinline__ unsigned pk4e4(float a, float b, float c, float d) {
#if __has_builtin(__builtin_amdgcn_cvt_pk_fp8_f32)
    unsigned u = 0;
    u = __builtin_amdgcn_cvt_pk_fp8_f32(a, b, u, false);
    u = __builtin_amdgcn_cvt_pk_fp8_f32(c, d, u, true);
    return u;
#else
    return (unsigned)f2e4(a) | ((unsigned)f2e4(b) << 8)
         | ((unsigned)f2e4(c) << 16) | ((unsigned)f2e4(d) << 24);
#endif
}

#define WSC 256.0f
#define FSC 64.0f
#define GSC 256.0f
#define ZDESC (1.0f / (WSC * FSC))
#define YDESC (1.0f / (WSC * GSC))
#define ZQ 1024.0f
#define ZS (1.0f / (16384.0f * 1024.0f))   // ZDESC / ZQ

// ---------------- W -> fp8 (both orientations), 64x64 tiles, 16B stores ----------------
__global__ __launch_bounds__(256) void wconvert_kernel(const float* __restrict__ W,
                                                       unsigned char* __restrict__ Wb8,
                                                       unsigned char* __restrict__ WT8) {
    __shared__ float t[64 * 68];
    const int k0 = blockIdx.x * 64, n0 = blockIdx.y * 64;
    const int tid = threadIdx.x;
    for (int c = tid; c < 1024; c += 256) {
        const int row = c >> 4, col4 = (c & 15) * 4;
        const float4 v = *(const float4*)(W + (size_t)(n0 + row) * KTOT + k0 + col4);
        *(float4*)&t[row * 68 + col4] = v;
    }
    __syncthreads();
    const int rr = tid >> 2, cb = (tid & 3) * 16;
    {
        uint4 o;
        const float* p = &t[rr * 68 + cb];
        o.x = pk4e4(p[0] * WSC,  p[1] * WSC,  p[2] * WSC,  p[3] * WSC);
        o.y = pk4e4(p[4] * WSC,  p[5] * WSC,  p[6] * WSC,  p[7] * WSC);
        o.z = pk4e4(p[8] * WSC,  p[9] * WSC,  p[10] * WSC, p[11] * WSC);
        o.w = pk4e4(p[12] * WSC, p[13] * WSC, p[14] * WSC, p[15] * WSC);
        *(uint4*)&Wb8[(size_t)(n0 + rr) * KTOT + k0 + cb] = o;
    }
    {
        uint4 o;
        const float* p = &t[cb * 68 + rr];
        o.x = pk4e4(p[0*68] * WSC,  p[1*68] * WSC,  p[2*68] * WSC,  p[3*68] * WSC);
        o.y = pk4e4(p[4*68] * WSC,  p[5*68] * WSC,  p[6*68] * WSC,  p[7*68] * WSC);
        o.z = pk4e4(p[8*68] * WSC,  p[9*68] * WSC,  p[10*68] * WSC, p[11*68] * WSC);
        o.w = pk4e4(p[12*68] * WSC, p[13*68] * WSC, p[14*68] * WSC, p[15*68] * WSC);
        *(uint4*)&WT8[(size_t)(k0 + rr) * NN + n0 + cb] = o;
    }
}

// ---------------- f0 -> fp8 (x64); also atomic-zero z_int + counters ----------------
__global__ __launch_bounds__(256) void cvt_f0_kernel(const float* __restrict__ f,
                                                     unsigned char* __restrict__ o,
                                                     int* __restrict__ z_int,
                                                     unsigned* __restrict__ cnt) {
    const int bid = blockIdx.x, tid = threadIdx.x;
    if (bid < 64) {
        int* zi = z_int + bid * 1024 + tid * 4;
        atomicExch(&zi[0], 0); atomicExch(&zi[1], 0);
        atomicExch(&zi[2], 0); atomicExch(&zi[3], 0);
    } else if (bid == 64 && tid < NSTEPS) {
        atomicExch(&cnt[tid], 0u);
    }
    const size_t i = ((size_t)bid * 256 + tid) * 4;
    const float4 v = *(const float4*)(f + i);
    uchar4 pk;
    pk.x = f2e4(v.x * FSC); pk.y = f2e4(v.y * FSC);
    pk.z = f2e4(v.z * FSC); pk.w = f2e4(v.w * FSC);
    *(uchar4*)(o + i) = pk;
}

// ---------------- conv-weight builders ----------------
__global__ __launch_bounds__(256) void wbuild_kernel(const float* __restrict__ wc,
                                                     ushort* __restrict__ wcA,
                                                     ushort* __restrict__ wcT) {
    const int bid = blockIdx.x, tid = threadIdx.x;
    if (bid < 64) {
        const int cy = bid;
        for (int k = tid; k < 416; k += 256) {
            const int tap = k >> 4, cx = k & 15;
            const float v = (tap < 25) ? wc[cy * 400 + cx * 25 + tap] : 0.f;
            wcA[cy * 416 + k] = f2b(v);
        }
    } else {
        const int cx = bid - 64;
        for (int k = tid; k < 1600; k += 256) {
            const int tap = k >> 6, cy = k & 63;
            wcT[cx * 1600 + k] = f2b(wc[cy * 400 + cx * 25 + tap]);
        }
    }
}

// ---------------- x0 std -> xcl fp32 [b][1024][16] + x16 bf16 ----------------
__global__ __launch_bounds__(256) void init_x_kernel(const float* __restrict__ x0,
                                                     float* __restrict__ xcl,
                                                     ushort* __restrict__ x16) {
    const int b = blockIdx.x, tid = threadIdx.x;
    __shared__ float xs[16384];
    for (int c = tid; c < 4096; c += 256)
        ((float4*)xs)[c] = ((const float4*)(x0 + (size_t)b * 16384))[c];
    __syncthreads();
    for (int p = tid; p < 1024; p += 256) {
        float v[16];
#pragma unroll
        for (int cx = 0; cx < 16; cx++) v[cx] = xs[cx * 1024 + p];
        float* dst = xcl + ((size_t)b * 1024 + p) * 16;
#pragma unroll
        for (int q = 0; q < 4; q++)
            *(float4*)(dst + q * 4) = make_float4(v[q*4], v[q*4+1], v[q*4+2], v[q*4+3]);
        uint4 u0, u1;
        u0.x = pk2(v[0], v[1]);  u0.y = pk2(v[2], v[3]);
        u0.z = pk2(v[4], v[5]);  u0.w = pk2(v[6], v[7]);
        u1.x = pk2(v[8], v[9]);  u1.y = pk2(v[10], v[11]);
        u1.z = pk2(v[12], v[13]); u1.w = pk2(v[14], v[15]);
        ushort* d16 = x16 + ((size_t)b * 1024 + p) * 16;
        *(uint4*)d16 = u0; *(uint4*)(d16 + 8) = u1;
    }
}

// ---------------- final: xcl -> d_out std ----------------
__global__ __launch_bounds__(256) void final_x_kernel(const float* __restrict__ xcl,
                                                      float* __restrict__ dout) {
    const int b = blockIdx.x, tid = threadIdx.x;
    __shared__ float xs[16384];
    for (int c = tid; c < 4096; c += 256)
        ((float4*)xs)[c] = ((const float4*)(xcl + (size_t)b * 16384))[c];
    __syncthreads();
    for (int idx = tid; idx < 16384; idx += 256) {
        const int cx = idx >> 10, p = idx & 1023;
        dout[(size_t)b * 16384 + idx] = xs[p * 16 + cx];
    }
}

// ---------------- f0 std -> f16pad [b][36][36][64] ----------------
__global__ __launch_bounds__(256) void init_fpad_kernel(const float* __restrict__ f0,
                                                        ushort* __restrict__ fpad) {
    const int b = blockIdx.x, rg = blockIdx.y;
    const int tid = threadIdx.x;
    __shared__ float fs[64 * 112];
    const float* src = f0 + (size_t)b * KTOT + rg * 112;
    for (int c = tid; c < 1792; c += 256) {
        const int cy = c / 28, p4 = (c % 28) * 4;
        *(float4*)&fs[cy * 112 + p4] = *(const float4*)(src + (size_t)cy * SP + p4);
    }
    __syncthreads();
    for (int c = tid; c < 896; c += 256) {
        const int pl = c >> 3, g8 = (c & 7) * 8;
        union { ushort u[8]; uint4 v; } pk;
#pragma unroll
        for (int e = 0; e < 8; e++) pk.u[e] = f2b(fs[(g8 + e) * 112 + pl]);
        const int pos = rg * 112 + pl, i = pos / 28, j = pos % 28;
        *(uint4*)(fpad + (((size_t)b * 36 + 4 + i) * 36 + 4 + j) * 64 + g8) = pk.v;
    }
}

// ---------------- GEMM1: fp8 split-K + int-atomic z accumulate + last-block softmax ----------------
__global__ __launch_bounds__(256, 3) void gemm1_kernel(const unsigned char* __restrict__ A,
                                                       const unsigned char* __restrict__ B,
                                                       int* __restrict__ z_int,
                                                       float* __restrict__ zscr,
                                                       unsigned char* __restrict__ g8,
                                                       unsigned* __restrict__ cnt) {
    const int bx = blockIdx.x, by = blockIdx.y;
    const int tid = threadIdx.x, l = tid & 63, w = tid >> 6;
    const int wr = w >> 1, wc = w & 1;
    const int lr = l & 15, lg = l >> 4;
    const int sw = (lr >> 1) & 3;
    const int hi8 = (lg & 1) * 8;
    __shared__ __attribute__((aligned(16))) unsigned char As[3 * 4096];
    __shared__ __attribute__((aligned(16))) unsigned char Bs[3 * 8192];

    floatx4 acc[2][4];
#pragma unroll
    for (int mi = 0; mi < 2; mi++)
#pragma unroll
        for (int ni = 0; ni < 4; ni++) acc[mi][ni] = (floatx4){0.f, 0.f, 0.f, 0.f};

    const size_t kbase = (size_t)by * 1024;

    auto STAGE = [&](int buf, int kc) {
        const size_t koff = kbase + (size_t)kc * 64;
        {
            const int row = tid >> 2;
            const int kk = (((tid & 3) ^ ((row >> 1) & 3)) << 4);
            __builtin_amdgcn_global_load_lds((gu32*)(A + (size_t)row * KTOT + koff + kk),
                                             (su32*)&As[buf * 4096 + tid * 16], 16, 0, 0);
        }
#pragma unroll
        for (int i = 0; i < 2; i++) {
            const int q = i * 256 + tid;
            const int rl = q >> 2;
            const int kk = (((q & 3) ^ ((rl >> 1) & 3)) << 4);
            const int row = bx * 128 + rl;
            __builtin_amdgcn_global_load_lds((gu32*)(B + (size_t)row * KTOT + koff + kk),
                                             (su32*)&Bs[buf * 8192 + q * 16], 16, 0, 0);
        }
    };

    STAGE(0, 0);
    int cur = 0;
#pragma unroll 1
    for (int kc = 0; kc < 16; kc++) {
        if (kc < 15) {
            int nb = cur + 1; if (nb == 3) nb = 0;
            STAGE(nb, kc + 1);
            asm volatile("s_waitcnt vmcnt(3)" ::: "memory");
        } else {
            asm volatile("s_waitcnt vmcnt(0)" ::: "memory");
        }
        __builtin_amdgcn_s_barrier();
#pragma unroll
        for (int kb = 0; kb < 2; kb++) {
            const int co = (((kb * 2 + (lg >> 1)) ^ sw) << 4) + hi8;
            long a[2];
#pragma unroll
            for (int mi = 0; mi < 2; mi++)
                a[mi] = *(const long*)&As[cur * 4096 + (wr * 32 + mi * 16 + lr) * 64 + co];
#pragma unroll
            for (int ni = 0; ni < 4; ni++) {
                const long b = *(const long*)&Bs[cur * 8192 + (wc * 64 + ni * 16 + lr) * 64 + co];
                acc[0][ni] = __builtin_amdgcn_mfma_f32_16x16x32_fp8_fp8(a[0], b, acc[0][ni], 0, 0, 0);
                acc[1][ni] = __builtin_amdgcn_mfma_f32_16x16x32_fp8_fp8(a[1], b, acc[1][ni], 0, 0, 0);
            }
        }
        cur = cur + 1; if (cur == 3) cur = 0;
    }
    // scatter partials as int32 fixed-point atomics (deterministic: int add commutative)
    int* zp = z_int + (wr * 32 + ((l >> 4) << 2)) * NN + bx * 128 + wc * 64 + (l & 15);
#pragma unroll
    for (int mi = 0; mi < 2; mi++)
#pragma unroll
        for (int ni = 0; ni < 4; ni++)
#pragma unroll
            for (int q = 0; q < 4; q++)
                atomicAdd(&zp[(mi * 16 + q) * NN + ni * 16],
                          (int)rintf(acc[mi][ni][q] * ZQ));

    // ---- last-block softmax finisher ----
    __threadfence();
    __syncthreads();
    __shared__ unsigned lastf;
    if (tid == 0) lastf = (atomicAdd(cnt, 1u) == (unsigned)(8 * NSPLIT - 1)) ? 1u : 0u;
    __syncthreads();
    if (lastf == 0u) return;
    __threadfence();

    const int r = tid >> 2, seg = tid & 3;
    float* scr = zscr + r * 1024;
    int* zi = z_int + r * 1024;
    float mx = -1e30f;
#pragma unroll 4
    for (int i = 0; i < 256; i++) {
        const int n = i * 4 + seg;
        const int v = atomicExch(&zi[n], 0);    // read + self-clean for next step
        const float zf = (float)v * ZS;
        scr[n] = zf;
        mx = fmaxf(mx, zf);
    }
    mx = fmaxf(mx, __shfl_xor(mx, 1));
    mx = fmaxf(mx, __shfl_xor(mx, 2));
    float ssum = 0.f;
#pragma unroll 4
    for (int i = 0; i < 256; i++) {
        const int n = i * 4 + seg;
        const float e = __expf(scr[n] - mx);
        scr[n] = e;
        ssum += e;
    }
    ssum += __shfl_xor(ssum, 1);
    ssum += __shfl_xor(ssum, 2);
    const float gsc = GSC / ssum;
    unsigned char* gout = g8 + r * 1024;
#pragma unroll 4
    for (int i = 0; i < 256; i++) {
        const int n = i * 4 + seg;
        gout[n] = f2e4(scr[n] * gsc);
    }
}

// ---------------- MERGED: convT (blocks 0..255) + GEMM2 (256..647), y out = bf16 ----------------
__global__ __launch_bounds__(256, 3) void gemm2_convT_kernel(const unsigned char* __restrict__ A,
                                                             const unsigned char* __restrict__ B,
                                                             ushort* __restrict__ y8,
                                                             const ushort* __restrict__ fpad,
                                                             const ushort* __restrict__ wcT,
                                                             const float* __restrict__ xin,
                                                             float* __restrict__ xout,
                                                             ushort* __restrict__ x16o) {
    __shared__ __attribute__((aligned(16))) unsigned char As[3 * 4096];
    __shared__ __attribute__((aligned(16))) unsigned char Bs[3 * 8192];
    const int tid = threadIdx.x, l = tid & 63, w = tid >> 6;
    const int lr = l & 15, lg = l >> 4;

    if (blockIdx.x < 256) {
        // ======== convT ========
        const int sub = blockIdx.x, b = sub & 63, pg = sub >> 6;
        floatx4 acc[4];
#pragma unroll
        for (int n = 0; n < 4; n++) acc[n] = (floatx4){0.f, 0.f, 0.f, 0.f};
        int p[4], p1[4], p2[4];
#pragma unroll
        for (int n = 0; n < 4; n++) {
            p[n]  = pg * 256 + (w * 4 + n) * 16 + lr;
            p1[n] = p[n] >> 5;
            p2[n] = p[n] & 31;
        }
        const ushort* fb_b = fpad + (size_t)b * (36 * 36 * 64);
        const int cy_lo = lg * 8;

        for (int s = 0; s < 50; s++) {
            const short8 af = *(const short8*)(wcT + (size_t)lr * 1600 + s * 32 + lg * 8);
            const int tap = s >> 1;
            const int ky = tap / 5, kx = tap % 5;
            const int cy_lane = ((s & 1) << 5) + cy_lo;
            short8 bf[4];
#pragma unroll
            for (int n = 0; n < 4; n++) {
                const size_t ad = (((size_t)(p1[n] + 4 - ky)) * 36 + (p2[n] + 4 - kx)) * 64 + cy_lane;
                bf[n] = *(const short8*)(fb_b + ad);
            }
#pragma unroll
            for (int n = 0; n < 4; n++)
                acc[n] = __builtin_amdgcn_mfma_f32_16x16x32_bf16(af, bf[n], acc[n], 0, 0, 0);
        }
#pragma unroll
        for (int n = 0; n < 4; n++) {
            const size_t base = ((size_t)b * 1024 + p[n]) * 16 + lg * 4;
            const float4 xo = *(const float4*)(xin + base);
            float4 r;
            r.x = 0.9f * xo.x + 0.1f * acc[n][0];
            r.y = 0.9f * xo.y + 0.1f * acc[n][1];
            r.z = 0.9f * xo.z + 0.1f * acc[n][2];
            r.w = 0.9f * xo.w + 0.1f * acc[n][3];
            *(float4*)(xout + base) = r;
            uint2 pk; pk.x = pk2(r.x, r.y); pk.y = pk2(r.z, r.w);
            *(uint2*)(x16o + base) = pk;
        }
        return;
    }

    // ======== gemm2 (swizzled, 3-deep) ========
    const int bx = blockIdx.x - 256;
    const int wr = w >> 1, wc = w & 1;
    const int sw = (lr >> 1) & 3;
    const int hi8 = (lg & 1) * 8;

    floatx4 acc[2][4];
#pragma unroll
    for (int mi = 0; mi < 2; mi++)
#pragma unroll
        for (int ni = 0; ni < 4; ni++) acc[mi][ni] = (floatx4){0.f, 0.f, 0.f, 0.f};

    auto STAGE = [&](int buf, int kc) {
        const size_t koff = (size_t)kc * 64;
        {
            const int row = tid >> 2;
            const int kk = (((tid & 3) ^ ((row >> 1) & 3)) << 4);
            __builtin_amdgcn_global_load_lds((gu32*)(A + (size_t)row * NN + koff + kk),
                                             (su32*)&As[buf * 4096 + tid * 16], 16, 0, 0);
        }
#pragma unroll
        for (int i = 0; i < 2; i++) {
            const int q = i * 256 + tid;
            const int rl = q >> 2;
            const int kk = (((q & 3) ^ ((rl >> 1) & 3)) << 4);
            const int row = bx * 128 + rl;
            __builtin_amdgcn_global_load_lds((gu32*)(B + (size_t)row * NN + koff + kk),
                                             (su32*)&Bs[buf * 8192 + q * 16], 16, 0, 0);
        }
    };

    STAGE(0, 0);
    int cur = 0;
#pragma unroll 1
    for (int kc = 0; kc < 16; kc++) {
        if (kc < 15) {
            int nb = cur + 1; if (nb == 3) nb = 0;
            STAGE(nb, kc + 1);
            asm volatile("s_waitcnt vmcnt(3)" ::: "memory");
        } else {
            asm volatile("s_waitcnt vmcnt(0)" ::: "memory");
        }
        __builtin_amdgcn_s_barrier();
#pragma unroll
        for (int kb = 0; kb < 2; kb++) {
            const int co = (((kb * 2 + (lg >> 1)) ^ sw) << 4) + hi8;
            long a[2];
#pragma unroll
            for (int mi = 0; mi < 2; mi++)
                a[mi] = *(const long*)&As[cur * 4096 + (wr * 32 + mi * 16 + lr) * 64 + co];
#pragma unroll
            for (int ni = 0; ni < 4; ni++) {
                const long b = *(const long*)&Bs[cur * 8192 + (wc * 64 + ni * 16 + lr) * 64 + co];
                acc[0][ni] = __builtin_amdgcn_mfma_f32_16x16x32_fp8_fp8(a[0], b, acc[0][ni], 0, 0, 0);
                acc[1][ni] = __builtin_amdgcn_mfma_f32_16x16x32_fp8_fp8(a[1], b, acc[1][ni], 0, 0, 0);
            }
        }
        cur = cur + 1; if (cur == 3) cur = 0;
    }
    ushort* cp = y8 + (size_t)(wr * 32 + ((l >> 4) << 2)) * KTOT
               + bx * 128 + wc * 64 + (l & 15);
#pragma unroll
    for (int mi = 0; mi < 2; mi++)
#pragma unroll
        for (int ni = 0; ni < 4; ni++)
#pragma unroll
            for (int q = 0; q < 4; q++)
                cp[(size_t)(mi * 16 + q) * KTOT + ni * 16] = f2b(acc[mi][ni][q] * YDESC);
}

// ---------------- MFMA conv + y(bf16) + channel-softmax -> f ----------------
__global__ __launch_bounds__(256) void conv_mfma_kernel(const ushort* __restrict__ x16,
                                                        const ushort* __restrict__ wcA,
                                                        const ushort* __restrict__ y8,
                                                        ushort* __restrict__ fpad,
                                                        unsigned char* __restrict__ f8std,
                                                        float* __restrict__ f32o,
                                                        const int write_f) {
    const int b = blockIdx.x, rg = blockIdx.y;
    const int tid = threadIdx.x, l = tid & 63, w = tid >> 6;
    const int lr = l & 15, lg = l >> 4;
    __shared__ float yt[64 * 196];
    ushort* ft = (ushort*)yt;

    {
        const ushort* yb = y8 + (size_t)b * KTOT + rg * 196;
        for (int c = tid; c < 3136; c += 256) {
            const int cy = c / 49, p4 = (c % 49) * 4;
            const uint2 u = *(const uint2*)(yb + (size_t)cy * SP + p4);
            yt[cy * 196 + p4 + 0] = b2f((ushort)(u.x & 0xffff));
            yt[cy * 196 + p4 + 1] = b2f((ushort)(u.x >> 16));
            yt[cy * 196 + p4 + 2] = b2f((ushort)(u.y & 0xffff));
            yt[cy * 196 + p4 + 3] = b2f((ushort)(u.y >> 16));
        }
    }

    const int nf = (w == 0) ? 4 : 3;
    const int fb = (w == 0) ? 0 : (1 + 3 * w);

    floatx4 acc[4][4];
#pragma unroll
    for (int m = 0; m < 4; m++)
#pragma unroll
        for (int n = 0; n < 4; n++) acc[m][n] = (floatx4){0.f, 0.f, 0.f, 0.f};

    int pos_l[4], ii[4], jj[4];
#pragma unroll
    for (int n = 0; n < 4; n++) {
        int pl = (fb + n) * 16 + lr;
        if (pl > 195) pl = 195;
        pos_l[n] = pl;
        ii[n] = rg * 7 + pl / 28;
        jj[n] = pl % 28;
    }

    const int t_lane = lg >> 1;
    const int cx0 = (lg & 1) * 8;
    const ushort* xb = x16 + ((size_t)b << 14);

    for (int s = 0; s < 13; s++) {
        short8 af[4];
#pragma unroll
        for (int m = 0; m < 4; m++)
            af[m] = *(const short8*)(wcA + (size_t)(m * 16 + lr) * 416 + s * 32 + lg * 8);
        const int tap = 2 * s + t_lane;
        const int ky = tap / 5, kx = tap % 5;
        short8 bf[4];
#pragma unroll
        for (int n = 0; n < 4; n++) {
            if (n < nf) {
                const int pp = (ii[n] + ky) * 32 + (jj[n] + kx);
                bf[n] = *(const short8*)(xb + (size_t)pp * 16 + cx0);
            }
        }
#pragma unroll
        for (int n = 0; n < 4; n++) {
            if (n < nf) {
#pragma unroll
                for (int m = 0; m < 4; m++)
                    acc[m][n] = __builtin_amdgcn_mfma_f32_16x16x32_bf16(af[m], bf[n], acc[m][n], 0, 0, 0);
            }
        }
    }
    __syncthreads();

#pragma unroll
    for (int n = 0; n < 4; n++) {
        if (n < nf) {
            float v[16];
#pragma unroll
            for (int m = 0; m < 4; m++)
#pragma unroll
                for (int q = 0; q < 4; q++) {
                    const int cy = m * 16 + lg * 4 + q;
                    v[m * 4 + q] = acc[m][n][q] + yt[cy * 196 + pos_l[n]];
                }
            float mx = v[0];
#pragma unroll
            for (int e = 1; e < 16; e++) mx = fmaxf(mx, v[e]);
            mx = fmaxf(mx, __shfl_xor(mx, 16));
            mx = fmaxf(mx, __shfl_xor(mx, 32));
            float ss = 0.f;
#pragma unroll
            for (int e = 0; e < 16; e++) { v[e] = __expf(v[e] - mx); ss += v[e]; }
            ss += __shfl_xor(ss, 16);
            ss += __shfl_xor(ss, 32);
            const float inv = 1.0f / ss;
            const bool valid = (((fb + n) * 16 + lr) < 196) && write_f;
            float* fo = f32o + (size_t)b * KTOT + rg * 196 + pos_l[n];
#pragma unroll
            for (int m = 0; m < 4; m++)
#pragma unroll
                for (int q = 0; q < 4; q++) {
                    const int cy = m * 16 + lg * 4 + q;
                    const float fv = v[m * 4 + q] * inv;
                    acc[m][n][q] = fv;
                    if (valid) fo[(size_t)cy * SP] = fv;
                }
        }
    }
    __syncthreads();

#pragma unroll
    for (int n = 0; n < 4; n++) {
        if (n < nf) {
#pragma unroll
            for (int m = 0; m < 4; m++)
#pragma unroll
                for (int q = 0; q < 4; q++)
                    ft[pos_l[n] * 72 + m * 16 + lg * 4 + q] = f2b(acc[m][n][q]);
        }
    }
    __syncthreads();

    for (int c = tid; c < 196 * 4; c += 256) {
        const int pl = c >> 2, ch = (c & 3) * 16;
        const uint4 v0 = *(const uint4*)&ft[pl * 72 + ch];
        const uint4 v1 = *(const uint4*)&ft[pl * 72 + ch + 8];
        const int gi = rg * 7 + pl / 28, gj = pl % 28;
        ushort* dst = fpad + (((size_t)b * 36 + 4 + gi) * 36 + 4 + gj) * 64 + ch;
        *(uint4*)dst = v0; *(uint4*)(dst + 8) = v1;
    }
    for (int c = tid; c < 1600; c += 256) {
        const int cy = c & 63, p8 = (c >> 6) * 8;
        if (p8 < 196) {
            union { unsigned char u[8]; unsigned w[2]; } pk;
#pragma unroll
            for (int e = 0; e < 8; e++)
                pk.u[e] = f2e4(b2f(ft[(p8 + e) * 72 + cy]) * FSC);
            unsigned* dst = (unsigned*)(f8std + (size_t)b * KTOT + (size_t)cy * SP + rg * 196 + p8);
            dst[0] = pk.w[0];
            if (p8 <= 188) dst[1] = pk.w[1];
        }
    }
}

extern "C" void kernel_launch(void* const* d_in, const int* in_sizes, int n_in,
                              void* d_out, int out_size, void* d_ws, size_t ws_size,
                              hipStream_t stream) {
    const float* x0    = (const float*)d_in[0];
    const float* f0    = (const float*)d_in[1];
    const float* wconv = (const float*)d_in[2];
    const float* W     = (const float*)d_in[3];

    const size_t XSZ = (size_t)BB * CXC * LL * LL;
    const size_t FSZ = (size_t)BB * KTOT;

    char* pp = (char*)d_ws;
    unsigned char* Wb8  = (unsigned char*)pp; pp += (size_t)NN * KTOT;
    unsigned char* WT8  = (unsigned char*)pp; pp += (size_t)NN * KTOT;
    float*  xcl0  = (float*)pp;  pp += (size_t)BB * 1024 * 16 * 4;
    float*  xcl1  = (float*)pp;  pp += (size_t)BB * 1024 * 16 * 4;
    ushort* x16a  = (ushort*)pp; pp += (size_t)BB * 1024 * 16 * 2;
    ushort* x16b  = (ushort*)pp; pp += (size_t)BB * 1024 * 16 * 2;
    pp += 4096;
    ushort* fpad  = (ushort*)pp; pp += (size_t)BB * 36 * 36 * 64 * 2;
    unsigned char* f8std = (unsigned char*)pp; pp += FSZ;
    ushort* y8    = (ushort*)pp; pp += FSZ * 2;                       // 6,422,528
    unsigned char* g8 = (unsigned char*)pp; pp += (size_t)BB * NN;
    int*    z_int = (int*)pp;    pp += (size_t)BB * NN * 4;           // 262,144
    float*  zscr  = (float*)pp;  pp += (size_t)BB * NN * 4;           // 262,144
    unsigned* cnt = (unsigned*)pp; pp += 4096;
    ushort* wcA   = (ushort*)pp; pp += (size_t)64 * 416 * 2;
    ushort* wcT   = (ushort*)pp; pp += (size_t)16 * 1600 * 2;
    // total ~137 MiB

    float*  xcl[2] = {xcl0, xcl1};
    ushort* x16[2] = {x16a, x16b};
    float*  f32o = (float*)d_out + XSZ;

    hipMemsetAsync(fpad, 0, (size_t)BB * 36 * 36 * 64 * 2, stream);
    hipMemsetAsync(x16a, 0, (size_t)BB * 1024 * 16 * 2 * 2 + 4096, stream);

    wconvert_kernel<<<dim3(KTOT / 64, NN / 64), 256, 0, stream>>>(W, Wb8, WT8);
    wbuild_kernel<<<80, 256, 0, stream>>>(wconv, wcA, wcT);
    init_x_kernel<<<64, 256, 0, stream>>>(x0, xcl0, x16a);
    cvt_f0_kernel<<<(int)(FSZ / 1024), 256, 0, stream>>>(f0, f8std, z_int, cnt);
    init_fpad_kernel<<<dim3(64, 7), 256, 0, stream>>>(f0, fpad);

    for (int t = 0; t < NSTEPS; t++) {
        const int cur = t & 1, nxt = cur ^ 1;
        gemm1_kernel<<<dim3(8, NSPLIT), 256, 0, stream>>>(f8std, Wb8, z_int, zscr, g8, cnt + t);
        gemm2_convT_kernel<<<256 + KTOT / 128, 256, 0, stream>>>(
            g8, WT8, y8, fpad, wcT, xcl[cur], xcl[nxt], x16[nxt]);
        conv_mfma_kernel<<<dim3(64, 4), 256, 0, stream>>>(x16[cur], wcA, y8, fpad, f8std, f32o,
                                                          t == NSTEPS - 1 ? 1 : 0);
    }
    final_x_kernel<<<64, 256, 0, stream>>>(xcl[0], (float*)d_out);
}

// Round 16
// 4245.622 us; speedup vs baseline: 2.8964x; 2.8964x over previous
//
#include <hip/hip_runtime.h>

#define BB 64
#define CXC 16
#define CYC 64
#define LL 32
#define MM 28
#define NN 1024
#define SP 784
#define KTOT 50176
#define NSTEPS 50
#define NSPLIT 49

using short8  = __attribute__((ext_vector_type(8))) short;
using floatx4 = __attribute__((ext_vector_type(4))) float;

typedef __attribute__((address_space(1))) unsigned int gu32;
typedef __attribute__((address_space(3))) unsigned int su32;

__device__ __forceinline__ ushort f2b(float v) {
    union { float f; unsigned u; } a; a.f = v;
    unsigned r = a.u + 0x7fff + ((a.u >> 16) & 1);   // RNE
    return (ushort)(r >> 16);
}
__device__ __forceinline__ unsigned pk2(float a, float b) {
    return (unsigned)f2b(a) | ((unsigned)f2b(b) << 16);
}
__device__ __forceinline__ float b2f(ushort u) {
    union { unsigned u; float f; } a; a.u = ((unsigned)u) << 16; return a.f;
}

// fp32 -> OCP e4m3fn, RNE, saturating at 448
__device__ __forceinline__ unsigned char f2e4(float v) {
    const unsigned u = __float_as_uint(v);
    const unsigned s = (u >> 24) & 0x80;
    float a = fabsf(v);
    if (a >= 448.f) return (unsigned char)(s | 0x7E);
    if (a < 0.015625f) {
        int q = (int)rintf(a * 512.f);
        return (unsigned char)(s | (unsigned)q);
    }
    unsigned au = u & 0x7fffffffu;
    unsigned r = au + 0xFFFFFu + ((au >> 20) & 1u);
    int exp = (int)(r >> 23) - 127;
    if (exp > 8) return (unsigned char)(s | 0x7E);
    unsigned mant = (r >> 20) & 7u;
    return (unsigned char)(s | (((unsigned)(exp + 7)) << 3) | mant);
}

__device__ __forceinline__ unsigned pk4e4(float a, float b, float c, float d) {
#if __has_builtin(__builtin_amdgcn_cvt_pk_fp8_f32)
    unsigned u = 0;
    u = __builtin_amdgcn_cvt_pk_fp8_f32(a, b, u, false);
    u = __builtin_amdgcn_cvt_pk_fp8_f32(c, d, u, true);
    return u;
#else
    return (unsigned)f2e4(a) | ((unsigned)f2e4(b) << 8)
         | ((unsigned)f2e4(c) << 16) | ((unsigned)f2e4(d) << 24);
#endif
}

#define WSC 256.0f
#define FSC 64.0f
#define GSC 256.0f
#define ZDESC (1.0f / (WSC * FSC))
#define YDESC (1.0f / (WSC * GSC))

// ---------------- W -> fp8 (both orientations), 64x64 tiles, 16B stores ----------------
__global__ __launch_bounds__(256) void wconvert_kernel(const float* __restrict__ W,
                                                       unsigned char* __restrict__ Wb8,
                                                       unsigned char* __restrict__ WT8) {
    __shared__ float t[64 * 68];
    const int k0 = blockIdx.x * 64, n0 = blockIdx.y * 64;
    const int tid = threadIdx.x;
    for (int c = tid; c < 1024; c += 256) {
        const int row = c >> 4, col4 = (c & 15) * 4;
        const float4 v = *(const float4*)(W + (size_t)(n0 + row) * KTOT + k0 + col4);
        *(float4*)&t[row * 68 + col4] = v;
    }
    __syncthreads();
    const int rr = tid >> 2, cb = (tid & 3) * 16;
    {
        uint4 o;
        const float* p = &t[rr * 68 + cb];
        o.x = pk4e4(p[0] * WSC,  p[1] * WSC,  p[2] * WSC,  p[3] * WSC);
        o.y = pk4e4(p[4] * WSC,  p[5] * WSC,  p[6] * WSC,  p[7] * WSC);
        o.z = pk4e4(p[8] * WSC,  p[9] * WSC,  p[10] * WSC, p[11] * WSC);
        o.w = pk4e4(p[12] * WSC, p[13] * WSC, p[14] * WSC, p[15] * WSC);
        *(uint4*)&Wb8[(size_t)(n0 + rr) * KTOT + k0 + cb] = o;
    }
    {
        uint4 o;
        const float* p = &t[cb * 68 + rr];
        o.x = pk4e4(p[0*68] * WSC,  p[1*68] * WSC,  p[2*68] * WSC,  p[3*68] * WSC);
        o.y = pk4e4(p[4*68] * WSC,  p[5*68] * WSC,  p[6*68] * WSC,  p[7*68] * WSC);
        o.z = pk4e4(p[8*68] * WSC,  p[9*68] * WSC,  p[10*68] * WSC, p[11*68] * WSC);
        o.w = pk4e4(p[12*68] * WSC, p[13*68] * WSC, p[14*68] * WSC, p[15*68] * WSC);
        *(uint4*)&WT8[(size_t)(k0 + rr) * NN + n0 + cb] = o;
    }
}

// ---------------- f0 -> fp8 (x64) ----------------
__global__ __launch_bounds__(256) void cvt_f0_kernel(const float* __restrict__ f,
                                                     unsigned char* __restrict__ o) {
    const size_t i = ((size_t)blockIdx.x * 256 + threadIdx.x) * 4;
    const float4 v = *(const float4*)(f + i);
    uchar4 pk;
    pk.x = f2e4(v.x * FSC); pk.y = f2e4(v.y * FSC);
    pk.z = f2e4(v.z * FSC); pk.w = f2e4(v.w * FSC);
    *(uchar4*)(o + i) = pk;
}

// ---------------- conv-weight builders ----------------
__global__ __launch_bounds__(256) void wbuild_kernel(const float* __restrict__ wc,
                                                     ushort* __restrict__ wcA,
                                                     ushort* __restrict__ wcT) {
    const int bid = blockIdx.x, tid = threadIdx.x;
    if (bid < 64) {
        const int cy = bid;
        for (int k = tid; k < 416; k += 256) {
            const int tap = k >> 4, cx = k & 15;
            const float v = (tap < 25) ? wc[cy * 400 + cx * 25 + tap] : 0.f;
            wcA[cy * 416 + k] = f2b(v);
        }
    } else {
        const int cx = bid - 64;
        for (int k = tid; k < 1600; k += 256) {
            const int tap = k >> 6, cy = k & 63;
            wcT[cx * 1600 + k] = f2b(wc[cy * 400 + cx * 25 + tap]);
        }
    }
}

// ---------------- x0 std -> xcl fp32 [b][1024][16] + x16 bf16 ----------------
__global__ __launch_bounds__(256) void init_x_kernel(const float* __restrict__ x0,
                                                     float* __restrict__ xcl,
                                                     ushort* __restrict__ x16) {
    const int b = blockIdx.x, tid = threadIdx.x;
    __shared__ float xs[16384];
    for (int c = tid; c < 4096; c += 256)
        ((float4*)xs)[c] = ((const float4*)(x0 + (size_t)b * 16384))[c];
    __syncthreads();
    for (int p = tid; p < 1024; p += 256) {
        float v[16];
#pragma unroll
        for (int cx = 0; cx < 16; cx++) v[cx] = xs[cx * 1024 + p];
        float* dst = xcl + ((size_t)b * 1024 + p) * 16;
#pragma unroll
        for (int q = 0; q < 4; q++)
            *(float4*)(dst + q * 4) = make_float4(v[q*4], v[q*4+1], v[q*4+2], v[q*4+3]);
        uint4 u0, u1;
        u0.x = pk2(v[0], v[1]);  u0.y = pk2(v[2], v[3]);
        u0.z = pk2(v[4], v[5]);  u0.w = pk2(v[6], v[7]);
        u1.x = pk2(v[8], v[9]);  u1.y = pk2(v[10], v[11]);
        u1.z = pk2(v[12], v[13]); u1.w = pk2(v[14], v[15]);
        ushort* d16 = x16 + ((size_t)b * 1024 + p) * 16;
        *(uint4*)d16 = u0; *(uint4*)(d16 + 8) = u1;
    }
}

// ---------------- final: xcl -> d_out std ----------------
__global__ __launch_bounds__(256) void final_x_kernel(const float* __restrict__ xcl,
                                                      float* __restrict__ dout) {
    const int b = blockIdx.x, tid = threadIdx.x;
    __shared__ float xs[16384];
    for (int c = tid; c < 4096; c += 256)
        ((float4*)xs)[c] = ((const float4*)(xcl + (size_t)b * 16384))[c];
    __syncthreads();
    for (int idx = tid; idx < 16384; idx += 256) {
        const int cx = idx >> 10, p = idx & 1023;
        dout[(size_t)b * 16384 + idx] = xs[p * 16 + cx];
    }
}

// ---------------- f0 std -> f16pad [b][36][36][64] ----------------
__global__ __launch_bounds__(256) void init_fpad_kernel(const float* __restrict__ f0,
                                                        ushort* __restrict__ fpad) {
    const int b = blockIdx.x, rg = blockIdx.y;
    const int tid = threadIdx.x;
    __shared__ float fs[64 * 112];
    const float* src = f0 + (size_t)b * KTOT + rg * 112;
    for (int c = tid; c < 1792; c += 256) {
        const int cy = c / 28, p4 = (c % 28) * 4;
        *(float4*)&fs[cy * 112 + p4] = *(const float4*)(src + (size_t)cy * SP + p4);
    }
    __syncthreads();
    for (int c = tid; c < 896; c += 256) {
        const int pl = c >> 3, g8 = (c & 7) * 8;
        union { ushort u[8]; uint4 v; } pk;
#pragma unroll
        for (int e = 0; e < 8; e++) pk.u[e] = f2b(fs[(g8 + e) * 112 + pl]);
        const int pos = rg * 112 + pl, i = pos / 28, j = pos % 28;
        *(uint4*)(fpad + (((size_t)b * 36 + 4 + i) * 36 + 4 + j) * 64 + g8) = pk.v;
    }
}

// ---------------- GEMM1: fp8 split-K, swizzled LDS, 3-deep rotation ----------------
__global__ __launch_bounds__(256, 3) void gemm1_kernel(const unsigned char* __restrict__ A,
                                                       const unsigned char* __restrict__ B,
                                                       float* __restrict__ C) {
    const int bx = blockIdx.x, by = blockIdx.y;
    const int tid = threadIdx.x, l = tid & 63, w = tid >> 6;
    const int wr = w >> 1, wc = w & 1;
    const int lr = l & 15, lg = l >> 4;
    const int sw = (lr >> 1) & 3;
    const int hi8 = (lg & 1) * 8;
    __shared__ __attribute__((aligned(16))) unsigned char As[3 * 4096];
    __shared__ __attribute__((aligned(16))) unsigned char Bs[3 * 8192];

    floatx4 acc[2][4];
#pragma unroll
    for (int mi = 0; mi < 2; mi++)
#pragma unroll
        for (int ni = 0; ni < 4; ni++) acc[mi][ni] = (floatx4){0.f, 0.f, 0.f, 0.f};

    const size_t kbase = (size_t)by * 1024;

    auto STAGE = [&](int buf, int kc) {
        const size_t koff = kbase + (size_t)kc * 64;
        {
            const int row = tid >> 2;
            const int kk = (((tid & 3) ^ ((row >> 1) & 3)) << 4);
            __builtin_amdgcn_global_load_lds((gu32*)(A + (size_t)row * KTOT + koff + kk),
                                             (su32*)&As[buf * 4096 + tid * 16], 16, 0, 0);
        }
#pragma unroll
        for (int i = 0; i < 2; i++) {
            const int q = i * 256 + tid;
            const int rl = q >> 2;
            const int kk = (((q & 3) ^ ((rl >> 1) & 3)) << 4);
            const int row = bx * 128 + rl;
            __builtin_amdgcn_global_load_lds((gu32*)(B + (size_t)row * KTOT + koff + kk),
                                             (su32*)&Bs[buf * 8192 + q * 16], 16, 0, 0);
        }
    };

    STAGE(0, 0);
    int cur = 0;
#pragma unroll 1
    for (int kc = 0; kc < 16; kc++) {
        if (kc < 15) {
            int nb = cur + 1; if (nb == 3) nb = 0;
            STAGE(nb, kc + 1);
            asm volatile("s_waitcnt vmcnt(3)" ::: "memory");
        } else {
            asm volatile("s_waitcnt vmcnt(0)" ::: "memory");
        }
        __builtin_amdgcn_s_barrier();
#pragma unroll
        for (int kb = 0; kb < 2; kb++) {
            const int co = (((kb * 2 + (lg >> 1)) ^ sw) << 4) + hi8;
            long a[2];
#pragma unroll
            for (int mi = 0; mi < 2; mi++)
                a[mi] = *(const long*)&As[cur * 4096 + (wr * 32 + mi * 16 + lr) * 64 + co];
#pragma unroll
            for (int ni = 0; ni < 4; ni++) {
                const long b = *(const long*)&Bs[cur * 8192 + (wc * 64 + ni * 16 + lr) * 64 + co];
                acc[0][ni] = __builtin_amdgcn_mfma_f32_16x16x32_fp8_fp8(a[0], b, acc[0][ni], 0, 0, 0);
                acc[1][ni] = __builtin_amdgcn_mfma_f32_16x16x32_fp8_fp8(a[1], b, acc[1][ni], 0, 0, 0);
            }
        }
        cur = cur + 1; if (cur == 3) cur = 0;
    }
    float* cp = C + (size_t)by * (BB * NN) + (size_t)(wr * 32 + ((l >> 4) << 2)) * NN
              + bx * 128 + wc * 64 + (l & 15);
#pragma unroll
    for (int mi = 0; mi < 2; mi++)
#pragma unroll
        for (int ni = 0; ni < 4; ni++)
#pragma unroll
            for (int q = 0; q < 4; q++)
                cp[(size_t)(mi * 16 + q) * NN + ni * 16] = acc[mi][ni][q];
}

// ---------------- fused: reduce 49 splits + row softmax -> g8 ----------------
__global__ __launch_bounds__(1024) void softmax_g_kernel(const float* __restrict__ zpart,
                                                         unsigned char* __restrict__ g8) {
    const int b = blockIdx.x, tid = threadIdx.x;
    float s = 0.f;
#pragma unroll 7
    for (int sp = 0; sp < NSPLIT; sp++) s += zpart[(size_t)sp * (BB * NN) + b * NN + tid];
    s *= ZDESC;
    __shared__ float red[32];
    float m = s;
#pragma unroll
    for (int off = 32; off > 0; off >>= 1) m = fmaxf(m, __shfl_down(m, off));
    if ((tid & 63) == 0) red[tid >> 6] = m;
    __syncthreads();
    float bm = red[0];
#pragma unroll
    for (int e = 1; e < 16; e++) bm = fmaxf(bm, red[e]);
    const float ev = __expf(s - bm);
    float ssum = ev;
#pragma unroll
    for (int off = 32; off > 0; off >>= 1) ssum += __shfl_down(ssum, off);
    __syncthreads();
    if ((tid & 63) == 0) red[16 + (tid >> 6)] = ssum;
    __syncthreads();
    float tot = red[16];
#pragma unroll
    for (int e = 1; e < 16; e++) tot += red[16 + e];
    g8[b * NN + tid] = f2e4(ev * (GSC / tot));
}

// ---------------- MERGED: convT (blocks 0..255) + GEMM2 (256..647), y out = bf16 ----------------
__global__ __launch_bounds__(256, 3) void gemm2_convT_kernel(const unsigned char* __restrict__ A,
                                                             const unsigned char* __restrict__ B,
                                                             ushort* __restrict__ y16,
                                                             const ushort* __restrict__ fpad,
                                                             const ushort* __restrict__ wcT,
                                                             const float* __restrict__ xin,
                                                             float* __restrict__ xout,
                                                             ushort* __restrict__ x16o) {
    __shared__ __attribute__((aligned(16))) unsigned char As[3 * 4096];
    __shared__ __attribute__((aligned(16))) unsigned char Bs[3 * 8192];
    const int tid = threadIdx.x, l = tid & 63, w = tid >> 6;
    const int lr = l & 15, lg = l >> 4;

    if (blockIdx.x < 256) {
        // ======== convT ========
        const int sub = blockIdx.x, b = sub & 63, pg = sub >> 6;
        floatx4 acc[4];
#pragma unroll
        for (int n = 0; n < 4; n++) acc[n] = (floatx4){0.f, 0.f, 0.f, 0.f};
        int p[4], p1[4], p2[4];
#pragma unroll
        for (int n = 0; n < 4; n++) {
            p[n]  = pg * 256 + (w * 4 + n) * 16 + lr;
            p1[n] = p[n] >> 5;
            p2[n] = p[n] & 31;
        }
        const ushort* fb_b = fpad + (size_t)b * (36 * 36 * 64);
        const int cy_lo = lg * 8;

        for (int s = 0; s < 50; s++) {
            const short8 af = *(const short8*)(wcT + (size_t)lr * 1600 + s * 32 + lg * 8);
            const int tap = s >> 1;
            const int ky = tap / 5, kx = tap % 5;
            const int cy_lane = ((s & 1) << 5) + cy_lo;
            short8 bf[4];
#pragma unroll
            for (int n = 0; n < 4; n++) {
                const size_t ad = (((size_t)(p1[n] + 4 - ky)) * 36 + (p2[n] + 4 - kx)) * 64 + cy_lane;
                bf[n] = *(const short8*)(fb_b + ad);
            }
#pragma unroll
            for (int n = 0; n < 4; n++)
                acc[n] = __builtin_amdgcn_mfma_f32_16x16x32_bf16(af, bf[n], acc[n], 0, 0, 0);
        }
#pragma unroll
        for (int n = 0; n < 4; n++) {
            const size_t base = ((size_t)b * 1024 + p[n]) * 16 + lg * 4;
            const float4 xo = *(const float4*)(xin + base);
            float4 r;
            r.x = 0.9f * xo.x + 0.1f * acc[n][0];
            r.y = 0.9f * xo.y + 0.1f * acc[n][1];
            r.z = 0.9f * xo.z + 0.1f * acc[n][2];
            r.w = 0.9f * xo.w + 0.1f * acc[n][3];
            *(float4*)(xout + base) = r;
            uint2 pk; pk.x = pk2(r.x, r.y); pk.y = pk2(r.z, r.w);
            *(uint2*)(x16o + base) = pk;
        }
        return;
    }

    // ======== gemm2 (swizzled, 3-deep) ========
    const int bx = blockIdx.x - 256;
    const int wr = w >> 1, wc = w & 1;
    const int sw = (lr >> 1) & 3;
    const int hi8 = (lg & 1) * 8;

    floatx4 acc[2][4];
#pragma unroll
    for (int mi = 0; mi < 2; mi++)
#pragma unroll
        for (int ni = 0; ni < 4; ni++) acc[mi][ni] = (floatx4){0.f, 0.f, 0.f, 0.f};

    auto STAGE = [&](int buf, int kc) {
        const size_t koff = (size_t)kc * 64;
        {
            const int row = tid >> 2;
            const int kk = (((tid & 3) ^ ((row >> 1) & 3)) << 4);
            __builtin_amdgcn_global_load_lds((gu32*)(A + (size_t)row * NN + koff + kk),
                                             (su32*)&As[buf * 4096 + tid * 16], 16, 0, 0);
        }
#pragma unroll
        for (int i = 0; i < 2; i++) {
            const int q = i * 256 + tid;
            const int rl = q >> 2;
            const int kk = (((q & 3) ^ ((rl >> 1) & 3)) << 4);
            const int row = bx * 128 + rl;
            __builtin_amdgcn_global_load_lds((gu32*)(B + (size_t)row * NN + koff + kk),
                                             (su32*)&Bs[buf * 8192 + q * 16], 16, 0, 0);
        }
    };

    STAGE(0, 0);
    int cur = 0;
#pragma unroll 1
    for (int kc = 0; kc < 16; kc++) {
        if (kc < 15) {
            int nb = cur + 1; if (nb == 3) nb = 0;
            STAGE(nb, kc + 1);
            asm volatile("s_waitcnt vmcnt(3)" ::: "memory");
        } else {
            asm volatile("s_waitcnt vmcnt(0)" ::: "memory");
        }
        __builtin_amdgcn_s_barrier();
#pragma unroll
        for (int kb = 0; kb < 2; kb++) {
            const int co = (((kb * 2 + (lg >> 1)) ^ sw) << 4) + hi8;
            long a[2];
#pragma unroll
            for (int mi = 0; mi < 2; mi++)
                a[mi] = *(const long*)&As[cur * 4096 + (wr * 32 + mi * 16 + lr) * 64 + co];
#pragma unroll
            for (int ni = 0; ni < 4; ni++) {
                const long b = *(const long*)&Bs[cur * 8192 + (wc * 64 + ni * 16 + lr) * 64 + co];
                acc[0][ni] = __builtin_amdgcn_mfma_f32_16x16x32_fp8_fp8(a[0], b, acc[0][ni], 0, 0, 0);
                acc[1][ni] = __builtin_amdgcn_mfma_f32_16x16x32_fp8_fp8(a[1], b, acc[1][ni], 0, 0, 0);
            }
        }
        cur = cur + 1; if (cur == 3) cur = 0;
    }
    ushort* cp = y16 + (size_t)(wr * 32 + ((l >> 4) << 2)) * KTOT
               + bx * 128 + wc * 64 + (l & 15);
#pragma unroll
    for (int mi = 0; mi < 2; mi++)
#pragma unroll
        for (int ni = 0; ni < 4; ni++)
#pragma unroll
            for (int q = 0; q < 4; q++)
                cp[(size_t)(mi * 16 + q) * KTOT + ni * 16] = f2b(acc[mi][ni][q] * YDESC);
}

// ---------------- MFMA conv + y(bf16) + channel-softmax -> f ----------------
__global__ __launch_bounds__(256) void conv_mfma_kernel(const ushort* __restrict__ x16,
                                                        const ushort* __restrict__ wcA,
                                                        const ushort* __restrict__ y16,
                                                        ushort* __restrict__ fpad,
                                                        unsigned char* __restrict__ f8std,
                                                        float* __restrict__ f32o,
                                                        const int write_f) {
    const int b = blockIdx.x, rg = blockIdx.y;
    const int tid = threadIdx.x, l = tid & 63, w = tid >> 6;
    const int lr = l & 15, lg = l >> 4;
    __shared__ float yt[64 * 196];
    ushort* ft = (ushort*)yt;

    {
        const ushort* yb = y16 + (size_t)b * KTOT + rg * 196;
        for (int c = tid; c < 3136; c += 256) {
            const int cy = c / 49, p4 = (c % 49) * 4;
            const uint2 u = *(const uint2*)(yb + (size_t)cy * SP + p4);
            yt[cy * 196 + p4 + 0] = b2f((ushort)(u.x & 0xffff));
            yt[cy * 196 + p4 + 1] = b2f((ushort)(u.x >> 16));
            yt[cy * 196 + p4 + 2] = b2f((ushort)(u.y & 0xffff));
            yt[cy * 196 + p4 + 3] = b2f((ushort)(u.y >> 16));
        }
    }

    const int nf = (w == 0) ? 4 : 3;
    const int fb = (w == 0) ? 0 : (1 + 3 * w);

    floatx4 acc[4][4];
#pragma unroll
    for (int m = 0; m < 4; m++)
#pragma unroll
        for (int n = 0; n < 4; n++) acc[m][n] = (floatx4){0.f, 0.f, 0.f, 0.f};

    int pos_l[4], ii[4], jj[4];
#pragma unroll
    for (int n = 0; n < 4; n++) {
        int pl = (fb + n) * 16 + lr;
        if (pl > 195) pl = 195;
        pos_l[n] = pl;
        ii[n] = rg * 7 + pl / 28;
        jj[n] = pl % 28;
    }

    const int t_lane = lg >> 1;
    const int cx0 = (lg & 1) * 8;
    const ushort* xb = x16 + ((size_t)b << 14);

    for (int s = 0; s < 13; s++) {
        short8 af[4];
#pragma unroll
        for (int m = 0; m < 4; m++)
            af[m] = *(const short8*)(wcA + (size_t)(m * 16 + lr) * 416 + s * 32 + lg * 8);
        const int tap = 2 * s + t_lane;
        const int ky = tap / 5, kx = tap % 5;
        short8 bf[4];
#pragma unroll
        for (int n = 0; n < 4; n++) {
            if (n < nf) {
                const int pp = (ii[n] + ky) * 32 + (jj[n] + kx);
                bf[n] = *(const short8*)(xb + (size_t)pp * 16 + cx0);
            }
        }
#pragma unroll
        for (int n = 0; n < 4; n++) {
            if (n < nf) {
#pragma unroll
                for (int m = 0; m < 4; m++)
                    acc[m][n] = __builtin_amdgcn_mfma_f32_16x16x32_bf16(af[m], bf[n], acc[m][n], 0, 0, 0);
            }
        }
    }
    __syncthreads();

#pragma unroll
    for (int n = 0; n < 4; n++) {
        if (n < nf) {
            float v[16];
#pragma unroll
            for (int m = 0; m < 4; m++)
#pragma unroll
                for (int q = 0; q < 4; q++) {
                    const int cy = m * 16 + lg * 4 + q;
                    v[m * 4 + q] = acc[m][n][q] + yt[cy * 196 + pos_l[n]];
                }
            float mx = v[0];
#pragma unroll
            for (int e = 1; e < 16; e++) mx = fmaxf(mx, v[e]);
            mx = fmaxf(mx, __shfl_xor(mx, 16));
            mx = fmaxf(mx, __shfl_xor(mx, 32));
            float ss = 0.f;
#pragma unroll
            for (int e = 0; e < 16; e++) { v[e] = __expf(v[e] - mx); ss += v[e]; }
            ss += __shfl_xor(ss, 16);
            ss += __shfl_xor(ss, 32);
            const float inv = 1.0f / ss;
            const bool valid = (((fb + n) * 16 + lr) < 196) && write_f;
            float* fo = f32o + (size_t)b * KTOT + rg * 196 + pos_l[n];
#pragma unroll
            for (int m = 0; m < 4; m++)
#pragma unroll
                for (int q = 0; q < 4; q++) {
                    const int cy = m * 16 + lg * 4 + q;
                    const float fv = v[m * 4 + q] * inv;
                    acc[m][n][q] = fv;
                    if (valid) fo[(size_t)cy * SP] = fv;
                }
        }
    }
    __syncthreads();

#pragma unroll
    for (int n = 0; n < 4; n++) {
        if (n < nf) {
#pragma unroll
            for (int m = 0; m < 4; m++)
#pragma unroll
                for (int q = 0; q < 4; q++)
                    ft[pos_l[n] * 72 + m * 16 + lg * 4 + q] = f2b(acc[m][n][q]);
        }
    }
    __syncthreads();

    for (int c = tid; c < 196 * 4; c += 256) {
        const int pl = c >> 2, ch = (c & 3) * 16;
        const uint4 v0 = *(const uint4*)&ft[pl * 72 + ch];
        const uint4 v1 = *(const uint4*)&ft[pl * 72 + ch + 8];
        const int gi = rg * 7 + pl / 28, gj = pl % 28;
        ushort* dst = fpad + (((size_t)b * 36 + 4 + gi) * 36 + 4 + gj) * 64 + ch;
        *(uint4*)dst = v0; *(uint4*)(dst + 8) = v1;
    }
    for (int c = tid; c < 1600; c += 256) {
        const int cy = c & 63, p8 = (c >> 6) * 8;
        if (p8 < 196) {
            union { unsigned char u[8]; unsigned w[2]; } pk;
#pragma unroll
            for (int e = 0; e < 8; e++)
                pk.u[e] = f2e4(b2f(ft[(p8 + e) * 72 + cy]) * FSC);
            unsigned* dst = (unsigned*)(f8std + (size_t)b * KTOT + (size_t)cy * SP + rg * 196 + p8);
            dst[0] = pk.w[0];
            if (p8 <= 188) dst[1] = pk.w[1];
        }
    }
}

extern "C" void kernel_launch(void* const* d_in, const int* in_sizes, int n_in,
                              void* d_out, int out_size, void* d_ws, size_t ws_size,
                              hipStream_t stream) {
    const float* x0    = (const float*)d_in[0];
    const float* f0    = (const float*)d_in[1];
    const float* wconv = (const float*)d_in[2];
    const float* W     = (const float*)d_in[3];

    const size_t XSZ = (size_t)BB * CXC * LL * LL;
    const size_t FSZ = (size_t)BB * KTOT;

    char* pp = (char*)d_ws;
    unsigned char* Wb8  = (unsigned char*)pp; pp += (size_t)NN * KTOT;
    unsigned char* WT8  = (unsigned char*)pp; pp += (size_t)NN * KTOT;
    float*  xcl0  = (float*)pp;  pp += (size_t)BB * 1024 * 16 * 4;
    float*  xcl1  = (float*)pp;  pp += (size_t)BB * 1024 * 16 * 4;
    ushort* x16a  = (ushort*)pp; pp += (size_t)BB * 1024 * 16 * 2;
    ushort* x16b  = (ushort*)pp; pp += (size_t)BB * 1024 * 16 * 2;
    pp += 4096;
    ushort* fpad  = (ushort*)pp; pp += (size_t)BB * 36 * 36 * 64 * 2;
    unsigned char* f8std = (unsigned char*)pp; pp += FSZ;
    ushort* y16   = (ushort*)pp; pp += FSZ * 2;                       // 6,422,528
    float*  zy    = (float*)pp;  pp += (size_t)NSPLIT * BB * NN * 4;  // 12,845,056
    unsigned char* g8 = (unsigned char*)pp; pp += (size_t)BB * NN;
    ushort* wcA   = (ushort*)pp; pp += (size_t)64 * 416 * 2;
    ushort* wcT   = (ushort*)pp; pp += (size_t)16 * 1600 * 2;
    // total ~149 MiB

    float*  xcl[2] = {xcl0, xcl1};
    ushort* x16[2] = {x16a, x16b};
    float*  f32o = (float*)d_out + XSZ;

    hipMemsetAsync(fpad, 0, (size_t)BB * 36 * 36 * 64 * 2, stream);
    hipMemsetAsync(x16a, 0, (size_t)BB * 1024 * 16 * 2 * 2 + 4096, stream);

    wconvert_kernel<<<dim3(KTOT / 64, NN / 64), 256, 0, stream>>>(W, Wb8, WT8);
    wbuild_kernel<<<80, 256, 0, stream>>>(wconv, wcA, wcT);
    init_x_kernel<<<64, 256, 0, stream>>>(x0, xcl0, x16a);
    cvt_f0_kernel<<<(int)(FSZ / 1024), 256, 0, stream>>>(f0, f8std);
    init_fpad_kernel<<<dim3(64, 7), 256, 0, stream>>>(f0, fpad);

    for (int t = 0; t < NSTEPS; t++) {
        const int cur = t & 1, nxt = cur ^ 1;
        gemm1_kernel<<<dim3(8, NSPLIT), 256, 0, stream>>>(f8std, Wb8, zy);
        softmax_g_kernel<<<BB, 1024, 0, stream>>>(zy, g8);
        gemm2_convT_kernel<<<256 + KTOT / 128, 256, 0, stream>>>(
            g8, WT8, y16, fpad, wcT, xcl[cur], xcl[nxt], x16[nxt]);
        conv_mfma_kernel<<<dim3(64, 4), 256, 0, stream>>>(x16[cur], wcA, y16, fpad, f8std, f32o,
                                                          t == NSTEPS - 1 ? 1 : 0);
    }
    final_x_kernel<<<64, 256, 0, stream>>>(xcl[0], (float*)d_out);
}